// Round 1
// baseline (775.108 us; speedup 1.0000x reference)
//
#include <hip/hip_runtime.h>
#include <math.h>

#define NLAT 64
#define NLON 128
#define HID  256
#define NSTA 1024
#define TG   32    // grid points (lons) per block, one lat row
#define SC   128   // station chunk
#define NCHUNK (NSTA / SC)

__device__ __forceinline__ float gelu_exact(float x) {
    // exact gelu: 0.5*x*(1+erf(x/sqrt(2)))  (matches jax approximate=False)
    return 0.5f * x * (1.0f + erff(x * 0.70710678118654752f));
}
__device__ __forceinline__ float softplus_f(float x) {
    // log(1+e^x) = max(x,0) + log1p(exp(-|x|))
    return fmaxf(x, 0.0f) + log1pf(expf(-fabsf(x)));
}

__global__ __launch_bounds__(256, 2)
void s2g_kernel(const float* __restrict__ feats,   // [2][1024][256]
                const float* __restrict__ coords,  // [2][1024][3]
                const float* __restrict__ maskp,   // [2][1024]
                const float* __restrict__ W1,      // [3][32]
                const float* __restrict__ b1,      // [32]
                const float* __restrict__ W2,      // [32]
                const float* __restrict__ b2p,     // [1]
                float* __restrict__ out)           // [2][256][64][128]
{
    __shared__ __align__(16) float vbuf[SC * TG];  // 16 KB: p-values; reused for epilogue reduction
    __shared__ float slat[SC], slon[SC], smask[SC];
    __shared__ float4 wpack[32];                   // (W1row0, W1row1, W1row2, b1) per hidden j
    __shared__ float w2s[32];
    __shared__ float maxbuf[8 * TG], psum[8 * TG];
    __shared__ float mS[TG], lS[TG], alphaS[TG];

    const int tid  = threadIdx.x;
    const int blk  = blockIdx.x & 255;     // 64 lat * 4 lon-blocks
    const int b    = blockIdx.x >> 8;      // batch
    const int lat  = blk >> 2;
    const int lon0 = (blk & 3) * TG;

    const float latv = -90.0f + (180.0f / 63.0f) * (float)lat;

    if (tid < 32) {
        wpack[tid] = make_float4(W1[tid], W1[32 + tid], W1[64 + tid], b1[tid]);
        w2s[tid]   = W2[tid];
        mS[tid]    = -3.0e38f;
        lS[tid]    = 0.0f;
    }
    const float b2 = b2p[0];

    // phase A mapping: thread -> (grid col gA, station group sgrp of 16)
    const int gA   = tid & 31;
    const int sgrp = tid >> 5;
    const float lonvA = -180.0f + (360.0f / 127.0f) * (float)(lon0 + gA);

    // phase C mapping: thread -> (feature cols {q, q+128}, station half h)
    const int q = tid & 127;
    const int h = tid >> 7;

    float acc0[TG], acc1[TG];
#pragma unroll
    for (int g = 0; g < TG; ++g) { acc0[g] = 0.0f; acc1[g] = 0.0f; }

    const float* cbase = coords + (size_t)b * NSTA * 3;
    const float* mbase = maskp  + (size_t)b * NSTA;
    const float* fb    = feats  + (size_t)b * NSTA * HID;

    for (int c = 0; c < NCHUNK; ++c) {
        const int s0 = c * SC;
        __syncthreads();   // prev chunk's phase C done with vbuf / staging
        if (tid < SC) {
            slat[tid]  = cbase[(size_t)(s0 + tid) * 3 + 0];
            slon[tid]  = cbase[(size_t)(s0 + tid) * 3 + 1];
            smask[tid] = mbase[s0 + tid];
        }
        __syncthreads();

        // ---- Phase A: scores for 16 stations at grid col gA (registers only)
        float dlat[16], dlon[16], dist[16], v[16];
#pragma unroll
        for (int i = 0; i < 16; ++i) {
            int s = sgrp * 16 + i;
            float dla = slat[s] - latv;
            float dlo = slon[s] - lonvA;
            dlat[i] = dla;
            dlon[i] = dlo;
            dist[i] = sqrtf(dla * dla + dlo * dlo + 1e-6f);
            v[i] = b2;  // accumulate layer-2 score, bias-initialized
        }
#pragma unroll 2
        for (int j = 0; j < 32; ++j) {
            float4 w = wpack[j];
            float w2 = w2s[j];
#pragma unroll
            for (int i = 0; i < 16; ++i) {
                float pre = w.w + w.x * dist[i] + w.y * dlat[i] + w.z * dlon[i];
                v[i] += w2 * gelu_exact(pre);
            }
        }
        float lmax = -3.0e38f;
#pragma unroll
        for (int i = 0; i < 16; ++i) {
            int s = sgrp * 16 + i;
            v[i] = softplus_f(v[i]) * smask[s];
            lmax = fmaxf(lmax, v[i]);
        }
        maxbuf[sgrp * TG + gA] = lmax;
        __syncthreads();

        // ---- B1: running max + rescale factor per grid col
        if (tid < TG) {
            float cm = maxbuf[tid];
#pragma unroll
            for (int k = 1; k < 8; ++k) cm = fmaxf(cm, maxbuf[k * TG + tid]);
            float mold = mS[tid];
            float mnew = fmaxf(mold, cm);
            alphaS[tid] = expf(mold - mnew);   // 0 on first chunk
            mS[tid] = mnew;
        }
        __syncthreads();

        // ---- B2: p = exp(v - m), write to vbuf, partial sums
        {
            float m  = mS[gA];
            float ps = 0.0f;
#pragma unroll
            for (int i = 0; i < 16; ++i) {
                int s = sgrp * 16 + i;
                float p = expf(v[i] - m);
                vbuf[s * TG + gA] = p;
                ps += p;
            }
            psum[sgrp * TG + gA] = ps;
        }
        __syncthreads();

        // ---- B3: denominator update (runs alongside phase C start)
        if (tid < TG) {
            float t = 0.0f;
#pragma unroll
            for (int k = 0; k < 8; ++k) t += psum[k * TG + tid];
            lS[tid] = lS[tid] * alphaS[tid] + t;
        }

        // ---- Phase C: rescale accumulators, accumulate this thread's 64 stations
#pragma unroll
        for (int g = 0; g < TG; ++g) {
            float a = alphaS[g];
            acc0[g] *= a;
            acc1[g] *= a;
        }
        const float* fch = fb + (size_t)(s0 + h * 64) * HID;
#pragma unroll 2
        for (int s = 0; s < 64; ++s) {
            const float* fr = fch + s * HID;
            float f0 = fr[q];
            float f1 = fr[q + 128];
            const float4* prow = reinterpret_cast<const float4*>(&vbuf[(h * 64 + s) * TG]);
#pragma unroll
            for (int gg = 0; gg < 8; ++gg) {
                float4 p4 = prow[gg];
                acc0[gg * 4 + 0] = fmaf(p4.x, f0, acc0[gg * 4 + 0]);
                acc0[gg * 4 + 1] = fmaf(p4.y, f0, acc0[gg * 4 + 1]);
                acc0[gg * 4 + 2] = fmaf(p4.z, f0, acc0[gg * 4 + 2]);
                acc0[gg * 4 + 3] = fmaf(p4.w, f0, acc0[gg * 4 + 3]);
                acc1[gg * 4 + 0] = fmaf(p4.x, f1, acc1[gg * 4 + 0]);
                acc1[gg * 4 + 1] = fmaf(p4.y, f1, acc1[gg * 4 + 1]);
                acc1[gg * 4 + 2] = fmaf(p4.z, f1, acc1[gg * 4 + 2]);
                acc1[gg * 4 + 3] = fmaf(p4.w, f1, acc1[gg * 4 + 3]);
            }
        }
    }
    __syncthreads();

    // ---- epilogue: reduce the two station-halves; layout [g][dp][q] = conflict-free
    float* red = vbuf;
    if (h == 1) {
#pragma unroll
        for (int g = 0; g < 16; ++g) {
            red[(g * 2 + 0) * 128 + q] = acc0[g];
            red[(g * 2 + 1) * 128 + q] = acc1[g];
        }
    }
    __syncthreads();
    if (h == 0) {
#pragma unroll
        for (int g = 0; g < 16; ++g) {
            acc0[g] += red[(g * 2 + 0) * 128 + q];
            acc1[g] += red[(g * 2 + 1) * 128 + q];
        }
    }
    __syncthreads();
    if (h == 0) {
#pragma unroll
        for (int g = 0; g < 16; ++g) {
            red[(g * 2 + 0) * 128 + q] = acc0[16 + g];
            red[(g * 2 + 1) * 128 + q] = acc1[16 + g];
        }
    }
    __syncthreads();
    if (h == 1) {
#pragma unroll
        for (int g = 0; g < 16; ++g) {
            acc0[16 + g] += red[(g * 2 + 0) * 128 + q];
            acc1[16 + g] += red[(g * 2 + 1) * 128 + q];
        }
    }
    __syncthreads();

    // ---- store: h==0 owns lons [lon0, lon0+16), h==1 owns [lon0+16, lon0+32)
#define STORE_HALF(GB)                                                               \
    do {                                                                             \
        float rl[16];                                                                \
        _Pragma("unroll") for (int k = 0; k < 16; ++k) rl[k] = 1.0f / lS[(GB) + k];  \
        size_t ob0 = ((size_t)(b * HID + q) * (NLAT * NLON)) +                       \
                     (size_t)lat * NLON + lon0 + (GB);                               \
        size_t ob1 = ob0 + (size_t)128 * NLAT * NLON;                                \
        _Pragma("unroll") for (int gv = 0; gv < 4; ++gv) {                           \
            float4 o;                                                                \
            o.x = acc0[(GB) + gv * 4 + 0] * rl[gv * 4 + 0];                          \
            o.y = acc0[(GB) + gv * 4 + 1] * rl[gv * 4 + 1];                          \
            o.z = acc0[(GB) + gv * 4 + 2] * rl[gv * 4 + 2];                          \
            o.w = acc0[(GB) + gv * 4 + 3] * rl[gv * 4 + 3];                          \
            *reinterpret_cast<float4*>(out + ob0 + gv * 4) = o;                      \
            o.x = acc1[(GB) + gv * 4 + 0] * rl[gv * 4 + 0];                          \
            o.y = acc1[(GB) + gv * 4 + 1] * rl[gv * 4 + 1];                          \
            o.z = acc1[(GB) + gv * 4 + 2] * rl[gv * 4 + 2];                          \
            o.w = acc1[(GB) + gv * 4 + 3] * rl[gv * 4 + 3];                          \
            *reinterpret_cast<float4*>(out + ob1 + gv * 4) = o;                      \
        }                                                                            \
    } while (0)

    if (h == 0) {
        STORE_HALF(0);
    } else {
        STORE_HALF(16);
    }
#undef STORE_HALF
}

extern "C" void kernel_launch(void* const* d_in, const int* in_sizes, int n_in,
                              void* d_out, int out_size, void* d_ws, size_t ws_size,
                              hipStream_t stream) {
    const float* feats  = (const float*)d_in[0];
    const float* coords = (const float*)d_in[1];
    const float* maskp  = (const float*)d_in[2];
    const float* W1     = (const float*)d_in[3];
    const float* b1     = (const float*)d_in[4];
    const float* W2     = (const float*)d_in[5];
    const float* b2     = (const float*)d_in[6];
    float* out          = (float*)d_out;

    dim3 grid(512);   // 2 batches * 64 lat rows * 4 lon-blocks of 32
    dim3 block(256);
    hipLaunchKernelGGL(s2g_kernel, grid, block, 0, stream,
                       feats, coords, maskp, W1, b1, W2, b2, out);
}

// Round 2
// 422.108 us; speedup vs baseline: 1.8363x; 1.8363x over previous
//
#include <hip/hip_runtime.h>
#include <math.h>

#define NLAT 64
#define NLON 128
#define HID  256
#define NSTA 1024
#define TG   32    // grid points (lons) per block, one lat row
#define SC   128   // station chunk
#define NCHUNK (NSTA / SC)

#define LOG2E 1.4426950408889634f
#define LN2   0.69314718055994531f

__device__ __forceinline__ float fexp(float x) {
    // e^x = 2^(x*log2e); v_exp_f32 (~1 ulp) — softmax-normalized, rel err irrelevant
    return __builtin_amdgcn_exp2f(x * LOG2E);
}

__device__ __forceinline__ float gelu_fast(float x) {
    // exact-gelu via Abramowitz-Stegun 7.1.26: erf(z)=1-(a1 t+..+a5 t^5)e^{-z^2},
    // t=1/(1+p z), |err|<=1.5e-7. Branchless, hw rcp/exp2. gelu err <= ~1e-6*|x|.
    const float p  = 0.3275911f;
    const float a1 = 0.254829592f, a2 = -0.284496736f, a3 = 1.421413741f,
                a4 = -1.453152027f, a5 = 1.061405429f;
    float z  = x * 0.70710678118654752f;     // x/sqrt(2)
    float az = fabsf(z);
    float t  = __builtin_amdgcn_rcpf(fmaf(p, az, 1.0f));
    float poly = fmaf(fmaf(fmaf(fmaf(a5, t, a4), t, a3), t, a2), t, a1) * t;
    float e  = __builtin_amdgcn_exp2f(az * az * -LOG2E);
    float r  = fmaf(-poly, e, 1.0f);         // erf(|z|) in [0,1)
    float erfz = copysignf(r, z);
    float hx = 0.5f * x;
    return fmaf(hx, erfz, hx);               // 0.5*x*(1+erf(z))
}

__device__ __forceinline__ float softplus_fast(float x) {
    // log(1+e^x) = max(x,0) + log(1+e^{-|x|}); hw exp2/log2
    float e = __builtin_amdgcn_exp2f(-fabsf(x) * LOG2E);
    float l = __builtin_amdgcn_logf(1.0f + e) * LN2;
    return fmaxf(x, 0.0f) + l;
}

__global__ __launch_bounds__(256, 2)
void s2g_kernel(const float* __restrict__ feats,   // [2][1024][256]
                const float* __restrict__ coords,  // [2][1024][3]
                const float* __restrict__ maskp,   // [2][1024]
                const float* __restrict__ W1,      // [3][32]
                const float* __restrict__ b1,      // [32]
                const float* __restrict__ W2,      // [32]
                const float* __restrict__ b2p,     // [1]
                float* __restrict__ out)           // [2][256][64][128]
{
    __shared__ __align__(16) float vbuf[SC * TG];  // 16 KB: p-values; reused for epilogue
    __shared__ float slat[SC], slon[SC], smask[SC];
    __shared__ float4 wpack[32];                   // (W1row0, W1row1, W1row2, b1)
    __shared__ float w2s[32];
    __shared__ float maxbuf[8 * TG], psum[8 * TG];
    __shared__ float mS[TG], lS[TG], alphaS[TG];

    const int tid  = threadIdx.x;
    const int blk  = blockIdx.x & 255;     // 64 lat * 4 lon-blocks
    const int b    = blockIdx.x >> 8;      // batch
    const int lat  = blk >> 2;
    const int lon0 = (blk & 3) * TG;

    const float latv = -90.0f + (180.0f / 63.0f) * (float)lat;

    if (tid < 32) {
        wpack[tid] = make_float4(W1[tid], W1[32 + tid], W1[64 + tid], b1[tid]);
        w2s[tid]   = W2[tid];
        mS[tid]    = -1.0e30f;
        lS[tid]    = 0.0f;
    }
    const float b2 = b2p[0];

    // phase A mapping: thread -> (grid col gA, station group sgrp of 16)
    const int gA   = tid & 31;
    const int sgrp = tid >> 5;
    const float lonvA = -180.0f + (360.0f / 127.0f) * (float)(lon0 + gA);

    // phase C mapping: thread -> (feature cols {q, q+128}, station half h)
    const int q = tid & 127;
    const int h = tid >> 7;

    float acc0[TG], acc1[TG];
#pragma unroll
    for (int g = 0; g < TG; ++g) { acc0[g] = 0.0f; acc1[g] = 0.0f; }

    const float* cbase = coords + (size_t)b * NSTA * 3;
    const float* mbase = maskp  + (size_t)b * NSTA;
    const float* fb    = feats  + (size_t)b * NSTA * HID;

    for (int c = 0; c < NCHUNK; ++c) {
        const int s0 = c * SC;
        __syncthreads();   // prev chunk's phase C done with vbuf / staging
        if (tid < SC) {
            slat[tid]  = cbase[(size_t)(s0 + tid) * 3 + 0];
            slon[tid]  = cbase[(size_t)(s0 + tid) * 3 + 1];
            smask[tid] = mbase[s0 + tid];
        }
        __syncthreads();

        // ---- Phase A: scores for 16 stations at grid col gA (registers only)
        float dlat[16], dlon[16], dist[16], v[16];
#pragma unroll
        for (int i = 0; i < 16; ++i) {
            int s = sgrp * 16 + i;
            float dla = slat[s] - latv;
            float dlo = slon[s] - lonvA;
            dlat[i] = dla;
            dlon[i] = dlo;
            dist[i] = sqrtf(dla * dla + dlo * dlo + 1e-6f);
            v[i] = b2;  // accumulate layer-2 score, bias-initialized
        }
#pragma unroll 2
        for (int j = 0; j < 32; ++j) {
            float4 w = wpack[j];
            float w2 = w2s[j];
#pragma unroll
            for (int i = 0; i < 16; ++i) {
                float pre = fmaf(w.x, dist[i], fmaf(w.y, dlat[i], fmaf(w.z, dlon[i], w.w)));
                v[i] = fmaf(w2, gelu_fast(pre), v[i]);
            }
        }
        float lmax = -3.0e38f;
#pragma unroll
        for (int i = 0; i < 16; ++i) {
            int s = sgrp * 16 + i;
            v[i] = softplus_fast(v[i]) * smask[s];
            lmax = fmaxf(lmax, v[i]);
        }
        maxbuf[sgrp * TG + gA] = lmax;
        __syncthreads();

        // ---- B1: running max + rescale factor per grid col
        if (tid < TG) {
            float cm = maxbuf[tid];
#pragma unroll
            for (int k = 1; k < 8; ++k) cm = fmaxf(cm, maxbuf[k * TG + tid]);
            float mold = mS[tid];
            float mnew = fmaxf(mold, cm);
            alphaS[tid] = fexp(mold - mnew);   // 0 on first chunk
            mS[tid] = mnew;
        }
        __syncthreads();

        // ---- B2: p = exp(v - m), write to vbuf, partial sums
        {
            float m  = mS[gA];
            float ps = 0.0f;
#pragma unroll
            for (int i = 0; i < 16; ++i) {
                int s = sgrp * 16 + i;
                float p = fexp(v[i] - m);
                vbuf[s * TG + gA] = p;
                ps += p;
            }
            psum[sgrp * TG + gA] = ps;
        }
        __syncthreads();

        // ---- B3: denominator update
        if (tid < TG) {
            float t = 0.0f;
#pragma unroll
            for (int k = 0; k < 8; ++k) t += psum[k * TG + tid];
            lS[tid] = lS[tid] * alphaS[tid] + t;
        }

        // ---- Phase C: rescale accumulators, accumulate this thread's 64 stations
#pragma unroll
        for (int g = 0; g < TG; ++g) {
            float a = alphaS[g];
            acc0[g] *= a;
            acc1[g] *= a;
        }
        const float* fch = fb + (size_t)(s0 + h * 64) * HID;
#pragma unroll 2
        for (int s = 0; s < 64; ++s) {
            const float* fr = fch + s * HID;
            float f0 = fr[q];
            float f1 = fr[q + 128];
            const float4* prow = reinterpret_cast<const float4*>(&vbuf[(h * 64 + s) * TG]);
#pragma unroll
            for (int gg = 0; gg < 8; ++gg) {
                float4 p4 = prow[gg];
                acc0[gg * 4 + 0] = fmaf(p4.x, f0, acc0[gg * 4 + 0]);
                acc0[gg * 4 + 1] = fmaf(p4.y, f0, acc0[gg * 4 + 1]);
                acc0[gg * 4 + 2] = fmaf(p4.z, f0, acc0[gg * 4 + 2]);
                acc0[gg * 4 + 3] = fmaf(p4.w, f0, acc0[gg * 4 + 3]);
                acc1[gg * 4 + 0] = fmaf(p4.x, f1, acc1[gg * 4 + 0]);
                acc1[gg * 4 + 1] = fmaf(p4.y, f1, acc1[gg * 4 + 1]);
                acc1[gg * 4 + 2] = fmaf(p4.z, f1, acc1[gg * 4 + 2]);
                acc1[gg * 4 + 3] = fmaf(p4.w, f1, acc1[gg * 4 + 3]);
            }
        }
    }
    __syncthreads();

    // ---- epilogue: reduce the two station-halves; layout [g][dp][q] = conflict-free
    float* red = vbuf;
    if (h == 1) {
#pragma unroll
        for (int g = 0; g < 16; ++g) {
            red[(g * 2 + 0) * 128 + q] = acc0[g];
            red[(g * 2 + 1) * 128 + q] = acc1[g];
        }
    }
    __syncthreads();
    if (h == 0) {
#pragma unroll
        for (int g = 0; g < 16; ++g) {
            acc0[g] += red[(g * 2 + 0) * 128 + q];
            acc1[g] += red[(g * 2 + 1) * 128 + q];
        }
    }
    __syncthreads();
    if (h == 0) {
#pragma unroll
        for (int g = 0; g < 16; ++g) {
            red[(g * 2 + 0) * 128 + q] = acc0[16 + g];
            red[(g * 2 + 1) * 128 + q] = acc1[16 + g];
        }
    }
    __syncthreads();
    if (h == 1) {
#pragma unroll
        for (int g = 0; g < 16; ++g) {
            acc0[16 + g] += red[(g * 2 + 0) * 128 + q];
            acc1[16 + g] += red[(g * 2 + 1) * 128 + q];
        }
    }
    __syncthreads();

    // ---- store: h==0 owns lons [lon0, lon0+16), h==1 owns [lon0+16, lon0+32)
#define STORE_HALF(GB)                                                               \
    do {                                                                             \
        float rl[16];                                                                \
        _Pragma("unroll") for (int k = 0; k < 16; ++k) rl[k] = 1.0f / lS[(GB) + k];  \
        size_t ob0 = ((size_t)(b * HID + q) * (NLAT * NLON)) +                       \
                     (size_t)lat * NLON + lon0 + (GB);                               \
        size_t ob1 = ob0 + (size_t)128 * NLAT * NLON;                                \
        _Pragma("unroll") for (int gv = 0; gv < 4; ++gv) {                           \
            float4 o;                                                                \
            o.x = acc0[(GB) + gv * 4 + 0] * rl[gv * 4 + 0];                          \
            o.y = acc0[(GB) + gv * 4 + 1] * rl[gv * 4 + 1];                          \
            o.z = acc0[(GB) + gv * 4 + 2] * rl[gv * 4 + 2];                          \
            o.w = acc0[(GB) + gv * 4 + 3] * rl[gv * 4 + 3];                          \
            *reinterpret_cast<float4*>(out + ob0 + gv * 4) = o;                      \
            o.x = acc1[(GB) + gv * 4 + 0] * rl[gv * 4 + 0];                          \
            o.y = acc1[(GB) + gv * 4 + 1] * rl[gv * 4 + 1];                          \
            o.z = acc1[(GB) + gv * 4 + 2] * rl[gv * 4 + 2];                          \
            o.w = acc1[(GB) + gv * 4 + 3] * rl[gv * 4 + 3];                          \
            *reinterpret_cast<float4*>(out + ob1 + gv * 4) = o;                      \
        }                                                                            \
    } while (0)

    if (h == 0) {
        STORE_HALF(0);
    } else {
        STORE_HALF(16);
    }
#undef STORE_HALF
}

extern "C" void kernel_launch(void* const* d_in, const int* in_sizes, int n_in,
                              void* d_out, int out_size, void* d_ws, size_t ws_size,
                              hipStream_t stream) {
    const float* feats  = (const float*)d_in[0];
    const float* coords = (const float*)d_in[1];
    const float* maskp  = (const float*)d_in[2];
    const float* W1     = (const float*)d_in[3];
    const float* b1     = (const float*)d_in[4];
    const float* W2     = (const float*)d_in[5];
    const float* b2     = (const float*)d_in[6];
    float* out          = (float*)d_out;

    dim3 grid(512);   // 2 batches * 64 lat rows * 4 lon-blocks of 32
    dim3 block(256);
    hipLaunchKernelGGL(s2g_kernel, grid, block, 0, stream,
                       feats, coords, maskp, W1, b1, W2, b2, out);
}

// Round 3
// 399.477 us; speedup vs baseline: 1.9403x; 1.0567x over previous
//
#include <hip/hip_runtime.h>
#include <math.h>

#define NLAT 64
#define NLON 128
#define HID  256
#define NSTA 1024
#define TG   16    // grid points (lons) per block -> 1024 blocks = 4/CU
#define SC   128   // station chunk
#define NCHUNK (NSTA / SC)
#define NGRP 16    // station groups in phase A (256 threads / TG)

#define LOG2E 1.4426950408889634f
#define LN2   0.69314718055994531f

typedef float v2f __attribute__((ext_vector_type(2)));

__device__ __forceinline__ v2f splat(float s) { return (v2f){s, s}; }
__device__ __forceinline__ v2f pkfma(v2f a, v2f b, v2f c) {
    return __builtin_elementwise_fma(a, b, c);   // v_pk_fma_f32 on gfx950
}
__device__ __forceinline__ v2f pkmax(v2f a, v2f b) {
    return __builtin_elementwise_max(a, b);      // v_pk_max_f32
}
// guaranteed packed FMA for the hot phase-C loop: d = a*b + d
__device__ __forceinline__ void pk_fma_acc(v2f& d, v2f a, v2f b) {
    asm("v_pk_fma_f32 %0, %1, %2, %0" : "+v"(d) : "v"(a), "v"(b));
}

__device__ __forceinline__ v2f gelu2(v2f x) {
    // exact-gelu via A&S 7.1.26 (|erf err|<=1.5e-7), packed full-rate math,
    // scalar hw rcp/exp2 per half.
    const float pC = 0.3275911f;
    const float a1 = 0.254829592f, a2 = -0.284496736f, a3 = 1.421413741f,
                a4 = -1.453152027f, a5 = 1.061405429f;
    v2f z  = x * 0.70710678118654752f;
    v2f az = pkmax(z, -z);
    v2f u  = pkfma(splat(pC), az, splat(1.0f));
    v2f t  = (v2f){__builtin_amdgcn_rcpf(u.x), __builtin_amdgcn_rcpf(u.y)};
    v2f poly = pkfma(pkfma(pkfma(pkfma(splat(a5), t, splat(a4)), t, splat(a3)),
                           t, splat(a2)), t, splat(a1)) * t;
    v2f zz   = z * z;
    v2f earg = zz * (-LOG2E);
    v2f e    = (v2f){__builtin_amdgcn_exp2f(earg.x), __builtin_amdgcn_exp2f(earg.y)};
    v2f r    = pkfma(-poly, e, splat(1.0f));     // erf(|z|)
    v2f erfz = (v2f){copysignf(r.x, z.x), copysignf(r.y, z.y)};
    v2f hx   = x * 0.5f;
    return pkfma(hx, erfz, hx);
}

__device__ __forceinline__ v2f softplus2(v2f x) {
    v2f ax   = pkmax(x, -x);
    v2f earg = ax * (-LOG2E);
    v2f e    = (v2f){__builtin_amdgcn_exp2f(earg.x), __builtin_amdgcn_exp2f(earg.y)};
    v2f op   = e + 1.0f;
    v2f l    = (v2f){__builtin_amdgcn_logf(op.x), __builtin_amdgcn_logf(op.y)};
    v2f mx   = pkmax(x, splat(0.0f));
    return pkfma(l, splat(LN2), mx);
}

__global__ __launch_bounds__(256, 4)
void s2g_kernel(const float* __restrict__ feats,   // [2][1024][256]
                const float* __restrict__ coords,  // [2][1024][3]
                const float* __restrict__ maskp,   // [2][1024]
                const float* __restrict__ W1,      // [3][32]
                const float* __restrict__ b1,      // [32]
                const float* __restrict__ W2,      // [32]
                const float* __restrict__ b2p,     // [1]
                float* __restrict__ out)           // [2][256][64][128]
{
    __shared__ __align__(16) float vbuf[SC * TG];  // 8 KB: p-values; reused for epilogue
    __shared__ __align__(16) float slat[SC], slon[SC], smask[SC];
    __shared__ float4 wpack[32];                   // (W1row0, W1row1, W1row2, b1)
    __shared__ float w2s[32];
    __shared__ __align__(16) float maxbuf[NGRP * TG], psum[NGRP * TG];
    __shared__ __align__(16) float mS[TG], lS[TG], alphaS[TG];

    const int tid  = threadIdx.x;
    const int blk  = blockIdx.x & 511;     // 64 lat * 8 lon-blocks
    const int b    = blockIdx.x >> 9;      // batch
    const int lat  = blk >> 3;
    const int lon0 = (blk & 7) * TG;

    const float latv = -90.0f + (180.0f / 63.0f) * (float)lat;

    if (tid < 32) {
        wpack[tid] = make_float4(W1[tid], W1[32 + tid], W1[64 + tid], b1[tid]);
        w2s[tid]   = W2[tid];
        if (tid < TG) { mS[tid] = -1.0e30f; lS[tid] = 0.0f; }
    }
    const float b2 = b2p[0];

    // phase A mapping: thread -> (grid col gA, station group sgrp of 8 = 4 pairs)
    const int gA   = tid & (TG - 1);
    const int sgrp = tid >> 4;             // 0..15
    const float lonvA = -180.0f + (360.0f / 127.0f) * (float)(lon0 + gA);

    // phase C mapping: thread -> (feature cols {q, q+128}, station half h)
    const int q = tid & 127;
    const int h = tid >> 7;

    v2f acc0p[8], acc1p[8];   // g-pairs: acc0p[gg] covers lons {2gg, 2gg+1} for d=q / d=q+128
#pragma unroll
    for (int gg = 0; gg < 8; ++gg) { acc0p[gg] = splat(0.0f); acc1p[gg] = splat(0.0f); }

    const float* cbase = coords + (size_t)b * NSTA * 3;
    const float* mbase = maskp  + (size_t)b * NSTA;
    const float* fb    = feats  + (size_t)b * NSTA * HID;

    for (int c = 0; c < NCHUNK; ++c) {
        const int s0 = c * SC;
        __syncthreads();   // prev chunk's phase C done with vbuf / staging
        if (tid < SC) {
            slat[tid]  = cbase[(size_t)(s0 + tid) * 3 + 0];
            slon[tid]  = cbase[(size_t)(s0 + tid) * 3 + 1];
            smask[tid] = mbase[s0 + tid];
        }
        __syncthreads();

        // ---- Phase A: scores for 8 stations (4 pairs) at grid col gA
        v2f dlat2[4], dlon2[4], dist2[4], v2a[4];
#pragma unroll
        for (int i = 0; i < 4; ++i) {
            int s = sgrp * 8 + 2 * i;
            v2f sl = *(const v2f*)&slat[s];
            v2f so = *(const v2f*)&slon[s];
            v2f dla = sl - latv;
            v2f dlo = so - lonvA;
            dlat2[i] = dla;
            dlon2[i] = dlo;
            v2f dd = pkfma(dla, dla, pkfma(dlo, dlo, splat(1e-6f)));
            dist2[i] = (v2f){sqrtf(dd.x), sqrtf(dd.y)};
            v2a[i] = splat(b2);
        }
#pragma unroll 2
        for (int j = 0; j < 32; ++j) {
            float4 w  = wpack[j];
            float  w2 = w2s[j];
            v2f wx = splat(w.x), wy = splat(w.y), wz = splat(w.z), wb = splat(w.w);
            v2f w22 = splat(w2);
#pragma unroll
            for (int i = 0; i < 4; ++i) {
                v2f pre = pkfma(wx, dist2[i], pkfma(wy, dlat2[i], pkfma(wz, dlon2[i], wb)));
                v2a[i] = pkfma(w22, gelu2(pre), v2a[i]);
            }
        }
        float lmax;
        {
#pragma unroll
            for (int i = 0; i < 4; ++i) {
                int s = sgrp * 8 + 2 * i;
                v2f mk = *(const v2f*)&smask[s];
                v2a[i] = softplus2(v2a[i]) * mk;
            }
            v2f m01 = pkmax(v2a[0], v2a[1]);
            v2f m23 = pkmax(v2a[2], v2a[3]);
            v2f mm  = pkmax(m01, m23);
            lmax = fmaxf(mm.x, mm.y);
        }
        maxbuf[sgrp * TG + gA] = lmax;
        __syncthreads();

        // ---- B1: running max + rescale factor per grid col
        if (tid < TG) {
            float cm = maxbuf[tid];
#pragma unroll
            for (int k = 1; k < NGRP; ++k) cm = fmaxf(cm, maxbuf[k * TG + tid]);
            float mold = mS[tid];
            float mnew = fmaxf(mold, cm);
            alphaS[tid] = __builtin_amdgcn_exp2f((mold - mnew) * LOG2E);
            mS[tid] = mnew;
        }
        __syncthreads();

        // ---- B2: p = exp(v - m), write to vbuf, partial sums
        {
            float m  = mS[gA];
            float ps = 0.0f;
#pragma unroll
            for (int i = 0; i < 4; ++i) {
                v2f arg = (v2a[i] - m) * LOG2E;
                float p0 = __builtin_amdgcn_exp2f(arg.x);
                float p1 = __builtin_amdgcn_exp2f(arg.y);
                int s = sgrp * 8 + 2 * i;
                vbuf[s * TG + gA]       = p0;
                vbuf[(s + 1) * TG + gA] = p1;
                ps += p0 + p1;
            }
            psum[sgrp * TG + gA] = ps;
        }
        __syncthreads();

        // ---- B3: denominator update
        if (tid < TG) {
            float t = 0.0f;
#pragma unroll
            for (int k = 0; k < NGRP; ++k) t += psum[k * TG + tid];
            lS[tid] = lS[tid] * alphaS[tid] + t;
        }

        // ---- Phase C: rescale accumulators, accumulate 64 stations (this half)
        {
            const v2f* alp = (const v2f*)alphaS;
#pragma unroll
            for (int gg = 0; gg < 8; ++gg) {
                v2f a2 = alp[gg];
                acc0p[gg] = acc0p[gg] * a2;
                acc1p[gg] = acc1p[gg] * a2;
            }
        }
        const float* fch = fb + (size_t)(s0 + h * 64) * HID;
#pragma unroll 2
        for (int s = 0; s < 64; ++s) {
            const float* fr = fch + s * HID;
            float f0 = fr[q];
            float f1 = fr[q + 128];
            v2f f0p = splat(f0);
            v2f f1p = splat(f1);
            const float4* prow = reinterpret_cast<const float4*>(&vbuf[(h * 64 + s) * TG]);
#pragma unroll
            for (int gg = 0; gg < 4; ++gg) {
                float4 p4 = prow[gg];
                v2f plo = (v2f){p4.x, p4.y};
                v2f phi = (v2f){p4.z, p4.w};
                pk_fma_acc(acc0p[2 * gg],     plo, f0p);
                pk_fma_acc(acc0p[2 * gg + 1], phi, f0p);
                pk_fma_acc(acc1p[2 * gg],     plo, f1p);
                pk_fma_acc(acc1p[2 * gg + 1], phi, f1p);
            }
        }
    }
    __syncthreads();

    // ---- epilogue: cross-half reduction via LDS (vbuf reused; 2048 floats needed)
    float a0[16], a1[16];
#pragma unroll
    for (int gg = 0; gg < 8; ++gg) {
        a0[2 * gg] = acc0p[gg].x; a0[2 * gg + 1] = acc0p[gg].y;
        a1[2 * gg] = acc1p[gg].x; a1[2 * gg + 1] = acc1p[gg].y;
    }
    float* red = vbuf;
    if (h == 1) {   // send partials for g in [0,8) (owned by h==0)
#pragma unroll
        for (int g = 0; g < 8; ++g) {
            red[(g * 2 + 0) * 128 + q] = a0[g];
            red[(g * 2 + 1) * 128 + q] = a1[g];
        }
    }
    __syncthreads();
    if (h == 0) {
#pragma unroll
        for (int g = 0; g < 8; ++g) {
            a0[g] += red[(g * 2 + 0) * 128 + q];
            a1[g] += red[(g * 2 + 1) * 128 + q];
        }
    }
    __syncthreads();
    if (h == 0) {   // send partials for g in [8,16) (owned by h==1)
#pragma unroll
        for (int g = 0; g < 8; ++g) {
            red[(g * 2 + 0) * 128 + q] = a0[8 + g];
            red[(g * 2 + 1) * 128 + q] = a1[8 + g];
        }
    }
    __syncthreads();
    if (h == 1) {
#pragma unroll
        for (int g = 0; g < 8; ++g) {
            a0[8 + g] += red[(g * 2 + 0) * 128 + q];
            a1[8 + g] += red[(g * 2 + 1) * 128 + q];
        }
    }

    // ---- store: h==0 owns lons [lon0, lon0+8), h==1 owns [lon0+8, lon0+16)
    {
        const int gb = h * 8;
        float rl[8];
#pragma unroll
        for (int k = 0; k < 8; ++k) rl[k] = 1.0f / lS[gb + k];
        size_t ob0 = ((size_t)(b * HID + q)) * (NLAT * NLON) +
                     (size_t)lat * NLON + lon0 + gb;
        size_t ob1 = ob0 + (size_t)128 * NLAT * NLON;
#pragma unroll
        for (int gv = 0; gv < 2; ++gv) {
            float4 o;
            o.x = a0[gb + gv * 4 + 0] * rl[gv * 4 + 0];
            o.y = a0[gb + gv * 4 + 1] * rl[gv * 4 + 1];
            o.z = a0[gb + gv * 4 + 2] * rl[gv * 4 + 2];
            o.w = a0[gb + gv * 4 + 3] * rl[gv * 4 + 3];
            *reinterpret_cast<float4*>(out + ob0 + gv * 4) = o;
            o.x = a1[gb + gv * 4 + 0] * rl[gv * 4 + 0];
            o.y = a1[gb + gv * 4 + 1] * rl[gv * 4 + 1];
            o.z = a1[gb + gv * 4 + 2] * rl[gv * 4 + 2];
            o.w = a1[gb + gv * 4 + 3] * rl[gv * 4 + 3];
            *reinterpret_cast<float4*>(out + ob1 + gv * 4) = o;
        }
    }
}

extern "C" void kernel_launch(void* const* d_in, const int* in_sizes, int n_in,
                              void* d_out, int out_size, void* d_ws, size_t ws_size,
                              hipStream_t stream) {
    const float* feats  = (const float*)d_in[0];
    const float* coords = (const float*)d_in[1];
    const float* maskp  = (const float*)d_in[2];
    const float* W1     = (const float*)d_in[3];
    const float* b1     = (const float*)d_in[4];
    const float* W2     = (const float*)d_in[5];
    const float* b2     = (const float*)d_in[6];
    float* out          = (float*)d_out;

    dim3 grid(1024);  // 2 batches * 64 lat rows * 8 lon-blocks of 16
    dim3 block(256);
    hipLaunchKernelGGL(s2g_kernel, grid, block, 0, stream,
                       feats, coords, maskp, W1, b1, W2, b2, out);
}

// Round 4
// 381.957 us; speedup vs baseline: 2.0293x; 1.0459x over previous
//
#include <hip/hip_runtime.h>
#include <math.h>

#define NLAT 64
#define NLON 128
#define HID  256
#define NSTA 1024
#define TG   16    // grid points (lons) per block = MFMA M
#define SC   128   // station chunk
#define NCHUNK (NSTA / SC)
#define NGRP 16    // station groups in phase A (256 threads / TG)

#define LOG2E 1.4426950408889634f
#define LN2   0.69314718055994531f

typedef float v2f __attribute__((ext_vector_type(2)));
typedef float f32x4 __attribute__((ext_vector_type(4)));
typedef _Float16 f16x8 __attribute__((ext_vector_type(8)));

__device__ __forceinline__ v2f splat(float s) { return (v2f){s, s}; }
__device__ __forceinline__ v2f pkfma(v2f a, v2f b, v2f c) {
    return __builtin_elementwise_fma(a, b, c);   // v_pk_fma_f32
}
__device__ __forceinline__ v2f pkmax(v2f a, v2f b) {
    return __builtin_elementwise_max(a, b);
}
__device__ __forceinline__ v2f pkmin(v2f a, v2f b) {
    return __builtin_elementwise_min(a, b);
}

// Trans-free exact-ish gelu. erf via A&S 7.1.28:
//   erf(z) = 1 - (1 + a1 z + ... + a6 z^6)^{-16},  z>=0, |err| <= 3e-7
// 1/u via deg-4 geometric series about c=1.955 + 2 Newton steps (u in [1,2.91]).
// Clamp z at 3.9 (erf(3.9)=1-3.5e-8). gelu abs err <= ~3e-5. All full-rate packed.
__device__ __forceinline__ v2f gelu2(v2f x) {
    const float A1 = 0.0705230784f, A2 = 0.0422820123f, A3 = 0.0092705272f,
                A4 = 0.0001520143f, A5 = 0.0002765672f, A6 = 0.0000430638f;
    const float RC = 0.5115089514f;              // 1/1.955
    v2f az = pkmax(x, -x);
    v2f za = pkmin(az * 0.70710678f, splat(3.9f));
    v2f u  = pkfma(za, splat(A6), splat(A5));
    u = pkfma(za, u, splat(A4));
    u = pkfma(za, u, splat(A3));
    u = pkfma(za, u, splat(A2));
    u = pkfma(za, u, splat(A1));
    u = pkfma(za, u, splat(1.0f));
    // w ~= 1/u
    v2f s = pkfma(u, splat(RC), splat(-1.0f));
    v2f p = splat(1.0f) - s;
    p = pkfma(-s, p, splat(1.0f));
    p = pkfma(-s, p, splat(1.0f));
    p = pkfma(-s, p, splat(1.0f));
    v2f w = p * RC;
    w = w * pkfma(-u, w, splat(2.0f));
    w = w * pkfma(-u, w, splat(2.0f));
    v2f w2 = w * w, w4 = w2 * w2, w8 = w4 * w4, w16 = w8 * w8;
    v2f t  = splat(1.0f) - w16;                  // erf(|z|)
    v2f hx = x * 0.5f;
    v2f ha = az * 0.5f;
    return pkfma(ha, t, hx);                     // 0.5x + 0.5|x|erf(|z|) = 0.5x(1+erf(z))
}

__device__ __forceinline__ v2f softplus2(v2f x) {
    v2f ax   = pkmax(x, -x);
    v2f earg = ax * (-LOG2E);
    v2f e    = (v2f){__builtin_amdgcn_exp2f(earg.x), __builtin_amdgcn_exp2f(earg.y)};
    v2f op   = e + 1.0f;
    v2f l    = (v2f){__builtin_amdgcn_logf(op.x), __builtin_amdgcn_logf(op.y)};
    v2f mx   = pkmax(x, splat(0.0f));
    return pkfma(l, splat(LN2), mx);
}

// ---- Kernel 0: feats [b][s][d] f32 -> F^T hi/lo [b][d][s] f16 (split for precision)
__global__ __launch_bounds__(256)
void cvt_kernel(const float* __restrict__ feats, _Float16* __restrict__ fhi,
                _Float16* __restrict__ flo) {
    __shared__ float tile[64][65];
    const int blk = blockIdx.x;            // b(2) * st(16) * dt(4)
    const int b  = blk >> 6;
    const int st = (blk >> 2) & 15;
    const int dt = blk & 3;
    const int x = threadIdx.x & 63, y = threadIdx.x >> 6;
#pragma unroll 4
    for (int k = 0; k < 16; ++k) {
        int s = k * 4 + y;
        tile[s][x] = feats[((size_t)(b * NSTA + st * 64 + s)) * HID + dt * 64 + x];
    }
    __syncthreads();
#pragma unroll 4
    for (int k = 0; k < 16; ++k) {
        int dl = k * 4 + y;
        float v = tile[x][dl];
        _Float16 hi = (_Float16)v;
        _Float16 lo = (_Float16)(v - (float)hi);
        size_t o = ((size_t)(b * HID + dt * 64 + dl)) * NSTA + st * 64 + x;
        fhi[o] = hi;
        flo[o] = lo;
    }
}

// ---- Main kernel: fused score MLP + online softmax + MFMA weighted sum
__global__ __launch_bounds__(256, 4)
void s2g_kernel(const float* __restrict__ coords,  // [2][1024][3]
                const float* __restrict__ maskp,   // [2][1024]
                const float* __restrict__ W1,      // [3][32]
                const float* __restrict__ b1,      // [32]
                const float* __restrict__ W2,      // [32]
                const float* __restrict__ b2p,     // [1]
                const _Float16* __restrict__ fhi,  // [2][256][1024]
                const _Float16* __restrict__ flo,  // [2][256][1024]
                float* __restrict__ out)           // [2][256][64][128]
{
    __shared__ __align__(16) f16x8 fragA[256];     // 4 KB: p in MFMA A-frag order [kc][lane]
    __shared__ __align__(16) float slat[SC], slon[SC], smask[SC];
    __shared__ float4 wpack[32];                   // (W1row0, W1row1, W1row2, b1)
    __shared__ float w2s[32];
    __shared__ __align__(16) float maxbuf[NGRP * TG], psum[NGRP * TG];
    __shared__ __align__(16) float mS[TG], lS[TG], alphaS[TG];

    const int tid  = threadIdx.x;
    const int blk  = blockIdx.x & 511;     // 64 lat * 8 lon-blocks
    const int b    = blockIdx.x >> 9;      // batch
    const int lat  = blk >> 3;
    const int lon0 = (blk & 7) * TG;

    const float latv = -90.0f + (180.0f / 63.0f) * (float)lat;

    if (tid < 32) {
        wpack[tid] = make_float4(W1[tid], W1[32 + tid], W1[64 + tid], b1[tid]);
        w2s[tid]   = W2[tid];
        if (tid < TG) { mS[tid] = -1.0e30f; lS[tid] = 0.0f; }
    }
    const float b2 = b2p[0];

    // phase A mapping: thread -> (grid col gA, station group sgrp of 8 = 4 pairs)
    const int gA   = tid & (TG - 1);
    const int sgrp = tid >> 4;             // 0..15
    const float lonvA = -180.0f + (360.0f / 127.0f) * (float)(lon0 + gA);

    // phase C mapping: wave w owns d in [w*64, w*64+64)
    const int lane = tid & 63;
    const int wv   = tid >> 6;

    f32x4 acc[4];
#pragma unroll
    for (int t = 0; t < 4; ++t) acc[t] = (f32x4){0.0f, 0.0f, 0.0f, 0.0f};

    const float* cbase = coords + (size_t)b * NSTA * 3;
    const float* mbase = maskp  + (size_t)b * NSTA;
    const _Float16* fhb = fhi + (size_t)b * HID * NSTA;
    const _Float16* flb = flo + (size_t)b * HID * NSTA;

    for (int c = 0; c < NCHUNK; ++c) {
        const int s0 = c * SC;
        __syncthreads();   // prev chunk's MFMA done with fragA / staging done
        if (tid < SC) {
            slat[tid]  = cbase[(size_t)(s0 + tid) * 3 + 0];
            slon[tid]  = cbase[(size_t)(s0 + tid) * 3 + 1];
            smask[tid] = mbase[s0 + tid];
        }
        __syncthreads();

        // ---- Phase A: scores for 8 stations (4 pairs) at grid col gA
        v2f dlat2[4], dlon2[4], dist2[4], v2a[4];
#pragma unroll
        for (int i = 0; i < 4; ++i) {
            int s = sgrp * 8 + 2 * i;
            v2f sl = *(const v2f*)&slat[s];
            v2f so = *(const v2f*)&slon[s];
            v2f dla = sl - latv;
            v2f dlo = so - lonvA;
            dlat2[i] = dla;
            dlon2[i] = dlo;
            v2f dd = pkfma(dla, dla, pkfma(dlo, dlo, splat(1e-6f)));
            dist2[i] = (v2f){sqrtf(dd.x), sqrtf(dd.y)};
            v2a[i] = splat(b2);
        }
#pragma unroll 2
        for (int j = 0; j < 32; ++j) {
            float4 wj = wpack[j];
            float  w2 = w2s[j];
            v2f wx = splat(wj.x), wy = splat(wj.y), wz = splat(wj.z), wb = splat(wj.w);
            v2f w22 = splat(w2);
#pragma unroll
            for (int i = 0; i < 4; ++i) {
                v2f pre = pkfma(wx, dist2[i], pkfma(wy, dlat2[i], pkfma(wz, dlon2[i], wb)));
                v2a[i] = pkfma(w22, gelu2(pre), v2a[i]);
            }
        }
        float lmax;
        {
#pragma unroll
            for (int i = 0; i < 4; ++i) {
                int s = sgrp * 8 + 2 * i;
                v2f mk = *(const v2f*)&smask[s];
                v2a[i] = softplus2(v2a[i]) * mk;
            }
            v2f m01 = pkmax(v2a[0], v2a[1]);
            v2f m23 = pkmax(v2a[2], v2a[3]);
            v2f mm  = pkmax(m01, m23);
            lmax = fmaxf(mm.x, mm.y);
        }
        maxbuf[sgrp * TG + gA] = lmax;
        __syncthreads();

        // ---- B1: running max + rescale factor per grid col
        if (tid < TG) {
            float cm = maxbuf[tid];
#pragma unroll
            for (int k = 1; k < NGRP; ++k) cm = fmaxf(cm, maxbuf[k * TG + tid]);
            float mold = mS[tid];
            float mnew = fmaxf(mold, cm);
            alphaS[tid] = __builtin_amdgcn_exp2f((mold - mnew) * LOG2E);
            mS[tid] = mnew;
        }
        __syncthreads();

        // ---- B2: p = exp(v-m) -> f16, store in A-frag layout, sum of ROUNDED p
        {
            float m  = mS[gA];
            float ps = 0.0f;
            f16x8 frag;
#pragma unroll
            for (int i = 0; i < 4; ++i) {
                v2f arg = (v2a[i] - m) * LOG2E;
                float p0 = __builtin_amdgcn_exp2f(arg.x);
                float p1 = __builtin_amdgcn_exp2f(arg.y);
                _Float16 h0 = (_Float16)p0, h1 = (_Float16)p1;
                frag[2 * i]     = h0;
                frag[2 * i + 1] = h1;
                ps += (float)h0 + (float)h1;   // exact normalization of quantized weights
            }
            // thread (gA, sgrp) == A-frag of lane ((sgrp&3)<<4)|gA for k-chunk sgrp>>2
            fragA[((sgrp >> 2) << 6) + (((sgrp & 3) << 4) | gA)] = frag;
            psum[sgrp * TG + gA] = ps;
        }
        __syncthreads();

        // ---- B3: denominator update (runs alongside phase C)
        if (tid < TG) {
            float t = 0.0f;
#pragma unroll
            for (int k = 0; k < NGRP; ++k) t += psum[k * TG + tid];
            lS[tid] = lS[tid] * alphaS[tid] + t;
        }

        // ---- Phase C: rescale accumulators (rows m = (lane>>4)*4+reg), MFMA
        {
            const f32x4 al = *(const f32x4*)&alphaS[(lane >> 4) * 4];
#pragma unroll
            for (int t = 0; t < 4; ++t) acc[t] = acc[t] * al;

            const int srow = s0 + ((lane >> 4) * 8);
            const int dbase = wv * 64 + (lane & 15);
#pragma unroll
            for (int kc = 0; kc < 4; ++kc) {
                f16x8 a = fragA[(kc << 6) + lane];
#pragma unroll
                for (int t = 0; t < 4; ++t) {
                    const size_t off = (size_t)(dbase + t * 16) * NSTA + srow + kc * 32;
                    f16x8 bh = *(const f16x8*)(fhb + off);
                    f16x8 bl = *(const f16x8*)(flb + off);
                    acc[t] = __builtin_amdgcn_mfma_f32_16x16x32_f16(a, bh, acc[t], 0, 0, 0);
                    acc[t] = __builtin_amdgcn_mfma_f32_16x16x32_f16(a, bl, acc[t], 0, 0, 0);
                }
            }
        }
    }
    __syncthreads();   // lS final

    // ---- epilogue: C rows = lons (m = (lane>>4)*4+reg), cols = d (lane&15)
    {
        const float4 l4 = *(const float4*)&lS[(lane >> 4) * 4];
        const float4 rl = make_float4(1.0f / l4.x, 1.0f / l4.y, 1.0f / l4.z, 1.0f / l4.w);
        const int m0 = (lane >> 4) * 4;
        const size_t gbase = (size_t)lat * NLON + lon0 + m0;
#pragma unroll
        for (int t = 0; t < 4; ++t) {
            const int d = wv * 64 + t * 16 + (lane & 15);
            float4 o;
            o.x = acc[t].x * rl.x;
            o.y = acc[t].y * rl.y;
            o.z = acc[t].z * rl.z;
            o.w = acc[t].w * rl.w;
            *reinterpret_cast<float4*>(out + ((size_t)(b * HID + d)) * (NLAT * NLON) + gbase) = o;
        }
    }
}

extern "C" void kernel_launch(void* const* d_in, const int* in_sizes, int n_in,
                              void* d_out, int out_size, void* d_ws, size_t ws_size,
                              hipStream_t stream) {
    const float* feats  = (const float*)d_in[0];
    const float* coords = (const float*)d_in[1];
    const float* maskp  = (const float*)d_in[2];
    const float* W1     = (const float*)d_in[3];
    const float* b1     = (const float*)d_in[4];
    const float* W2     = (const float*)d_in[5];
    const float* b2     = (const float*)d_in[6];
    float* out          = (float*)d_out;

    _Float16* fhi = (_Float16*)d_ws;                     // [2][256][1024] = 1 MB
    _Float16* flo = fhi + (size_t)2 * HID * NSTA;        // [2][256][1024] = 1 MB

    hipLaunchKernelGGL(cvt_kernel, dim3(128), dim3(256), 0, stream, feats, fhi, flo);
    hipLaunchKernelGGL(s2g_kernel, dim3(1024), dim3(256), 0, stream,
                       coords, maskp, W1, b1, W2, b2, fhi, flo, out);
}

// Round 5
// 283.110 us; speedup vs baseline: 2.7378x; 1.3491x over previous
//
#include <hip/hip_runtime.h>
#include <math.h>

#define NLAT 64
#define NLON 128
#define HID  256
#define NSTA 1024
#define TG   16    // grid points (lons) per block = MFMA M
#define SC   128   // station chunk
#define NCHUNK (NSTA / SC)
#define NGRP 16    // station groups in phase A (256 threads / TG)

#define LOG2E 1.4426950408889634f
#define LN2   0.69314718055994531f
// gelu sigma-form constants: Phi(x) ~= sigma(1.5957691x + 0.0713548x^3)
// exp2 arg = -(u)*log2e = GA*x + GB*x^3
#define GA (-2.3022082f)
#define GB (-0.1029432f)

typedef float f32x4 __attribute__((ext_vector_type(4)));
typedef _Float16 f16x8 __attribute__((ext_vector_type(8)));

// ---- Kernel 0: feats [b][s][d] f32 -> F^T hi/lo [b][d][s] f16 (split for precision)
__global__ __launch_bounds__(256)
void cvt_kernel(const float* __restrict__ feats, _Float16* __restrict__ fhi,
                _Float16* __restrict__ flo) {
    __shared__ float tile[64][65];
    const int blk = blockIdx.x;            // b(2) * st(16) * dt(4)
    const int b  = blk >> 6;
    const int st = (blk >> 2) & 15;
    const int dt = blk & 3;
    const int x = threadIdx.x & 63, y = threadIdx.x >> 6;
#pragma unroll 4
    for (int k = 0; k < 16; ++k) {
        int s = k * 4 + y;
        tile[s][x] = feats[((size_t)(b * NSTA + st * 64 + s)) * HID + dt * 64 + x];
    }
    __syncthreads();
#pragma unroll 4
    for (int k = 0; k < 16; ++k) {
        int dl = k * 4 + y;
        float v = tile[x][dl];
        _Float16 hi = (_Float16)v;
        _Float16 lo = (_Float16)(v - (float)hi);
        size_t o = ((size_t)(b * HID + dt * 64 + dl)) * NSTA + st * 64 + x;
        fhi[o] = hi;
        flo[o] = lo;
    }
}

// ---- Main kernel: fused score MLP + online softmax + MFMA weighted sum
__global__ __launch_bounds__(256, 4)
void s2g_kernel(const float* __restrict__ coords,  // [2][1024][3]
                const float* __restrict__ maskp,   // [2][1024]
                const float* __restrict__ W1,      // [3][32]
                const float* __restrict__ b1,      // [32]
                const float* __restrict__ W2,      // [32]
                const float* __restrict__ b2p,     // [1]
                const _Float16* __restrict__ fhi,  // [2][256][1024]
                const _Float16* __restrict__ flo,  // [2][256][1024]
                float* __restrict__ out)           // [2][256][64][128]
{
    __shared__ __align__(16) f16x8 fragAh[256];    // 4 KB: P-hi in MFMA A-frag order
    __shared__ __align__(16) f16x8 fragAl[256];    // 4 KB: P-lo
    __shared__ __align__(16) float slat[SC], slon[SC], smask[SC];
    __shared__ float4 wpack[32];                   // (W1row0, W1row1, W1row2, b1)
    __shared__ float w2s[32];
    __shared__ __align__(16) float maxbuf[NGRP * TG], psum[NGRP * TG];
    __shared__ __align__(16) float mS[TG], lS[TG], alphaS[TG];

    const int tid  = threadIdx.x;
    const int blk  = blockIdx.x & 511;     // 64 lat * 8 lon-blocks
    const int b    = blockIdx.x >> 9;      // batch
    const int lat  = blk >> 3;
    const int lon0 = (blk & 7) * TG;

    const float latv = -90.0f + (180.0f / 63.0f) * (float)lat;

    if (tid < 32) {
        wpack[tid] = make_float4(W1[tid], W1[32 + tid], W1[64 + tid], b1[tid]);
        w2s[tid]   = W2[tid];
        if (tid < TG) { mS[tid] = -1.0e30f; lS[tid] = 0.0f; }
    }
    const float b2 = b2p[0];

    // phase A mapping: thread -> (grid col gA, station group sgrp of 8)
    const int gA   = tid & (TG - 1);
    const int sgrp = tid >> 4;             // 0..15
    const float lonvA = -180.0f + (360.0f / 127.0f) * (float)(lon0 + gA);

    // phase C mapping: wave w owns d in [w*64, w*64+64)
    const int lane = tid & 63;
    const int wv   = tid >> 6;

    f32x4 acc[4];
#pragma unroll
    for (int t = 0; t < 4; ++t) acc[t] = (f32x4){0.0f, 0.0f, 0.0f, 0.0f};

    const float* cbase = coords + (size_t)b * NSTA * 3;
    const float* mbase = maskp  + (size_t)b * NSTA;
    const _Float16* fhb = fhi + (size_t)b * HID * NSTA;
    const _Float16* flb = flo + (size_t)b * HID * NSTA;

    for (int c = 0; c < NCHUNK; ++c) {
        const int s0 = c * SC;
        __syncthreads();   // prev chunk's MFMA done with frags / staging done
        if (tid < SC) {
            slat[tid]  = cbase[(size_t)(s0 + tid) * 3 + 0];
            slon[tid]  = cbase[(size_t)(s0 + tid) * 3 + 1];
            smask[tid] = mbase[s0 + tid];
        }
        __syncthreads();

        // ---- Phase A: scores for 8 stations at grid col gA (sigma-form gelu)
        float dist[8], dlat[8], dlon[8], v[8];
#pragma unroll
        for (int i = 0; i < 8; ++i) {
            int s = sgrp * 8 + i;
            float dla = slat[s] - latv;
            float dlo = slon[s] - lonvA;
            dlat[i] = dla;
            dlon[i] = dlo;
            dist[i] = sqrtf(fmaf(dla, dla, fmaf(dlo, dlo, 1e-6f)));
            v[i] = b2;
        }
#pragma unroll 2
        for (int j = 0; j < 32; ++j) {
            float4 wj = wpack[j];
            float  w2 = w2s[j];
#pragma unroll
            for (int i = 0; i < 8; ++i) {
                float pre  = fmaf(wj.x, dist[i], fmaf(wj.y, dlat[i], fmaf(wj.z, dlon[i], wj.w)));
                float t    = pre * pre;
                float earg = fmaf(GB, t, GA) * pre;            // -u*log2e
                float e    = __builtin_amdgcn_exp2f(earg);
                float r    = __builtin_amdgcn_rcpf(1.0f + e);  // sigma(u) = Phi(pre)
                v[i] = fmaf(w2 * pre, r, v[i]);                // += w2 * gelu(pre)
            }
        }
        float lmax = -3.0e38f;
#pragma unroll
        for (int i = 0; i < 8; ++i) {
            int s = sgrp * 8 + i;
            float x  = v[i];
            float ax = fabsf(x);
            float e  = __builtin_amdgcn_exp2f(-ax * LOG2E);
            float sp = fmaxf(x, 0.0f) + __builtin_amdgcn_logf(1.0f + e) * LN2;
            v[i] = sp * smask[s];
            lmax = fmaxf(lmax, v[i]);
        }
        maxbuf[sgrp * TG + gA] = lmax;
        __syncthreads();

        // ---- B1: running max + rescale factor per grid col
        if (tid < TG) {
            float cm = maxbuf[tid];
#pragma unroll
            for (int k = 1; k < NGRP; ++k) cm = fmaxf(cm, maxbuf[k * TG + tid]);
            float mold = mS[tid];
            float mnew = fmaxf(mold, cm);
            alphaS[tid] = __builtin_amdgcn_exp2f((mold - mnew) * LOG2E);
            mS[tid] = mnew;
        }
        __syncthreads();

        // ---- B2: p = exp(v-m) -> f16 hi+lo, A-frag layout; sum fp32 p
        {
            float m  = mS[gA];
            float ps = 0.0f;
            f16x8 fh, fl;
#pragma unroll
            for (int i = 0; i < 8; ++i) {
                float p = __builtin_amdgcn_exp2f((v[i] - m) * LOG2E);
                _Float16 h = (_Float16)p;
                fh[i] = h;
                fl[i] = (_Float16)(p - (float)h);
                ps += p;
            }
            const int idx = ((sgrp >> 2) << 6) + (((sgrp & 3) << 4) | gA);
            fragAh[idx] = fh;
            fragAl[idx] = fl;
            psum[sgrp * TG + gA] = ps;
        }
        __syncthreads();

        // ---- B3: denominator update (runs alongside phase C)
        if (tid < TG) {
            float t = 0.0f;
#pragma unroll
            for (int k = 0; k < NGRP; ++k) t += psum[k * TG + tid];
            lS[tid] = lS[tid] * alphaS[tid] + t;
        }

        // ---- Phase C: rescale accumulators (rows m = (lane>>4)*4+reg), MFMA
        {
            const f32x4 al = *(const f32x4*)&alphaS[(lane >> 4) * 4];
#pragma unroll
            for (int t = 0; t < 4; ++t) acc[t] = acc[t] * al;

            const int srow = s0 + ((lane >> 4) * 8);
            const int dbase = wv * 64 + (lane & 15);
#pragma unroll
            for (int kc = 0; kc < 4; ++kc) {
                f16x8 ah = fragAh[(kc << 6) + lane];
                f16x8 al16 = fragAl[(kc << 6) + lane];
#pragma unroll
                for (int t = 0; t < 4; ++t) {
                    const size_t off = (size_t)(dbase + t * 16) * NSTA + srow + kc * 32;
                    f16x8 bh = *(const f16x8*)(fhb + off);
                    f16x8 bl = *(const f16x8*)(flb + off);
                    acc[t] = __builtin_amdgcn_mfma_f32_16x16x32_f16(ah, bh, acc[t], 0, 0, 0);
                    acc[t] = __builtin_amdgcn_mfma_f32_16x16x32_f16(ah, bl, acc[t], 0, 0, 0);
                    acc[t] = __builtin_amdgcn_mfma_f32_16x16x32_f16(al16, bh, acc[t], 0, 0, 0);
                }
            }
        }
    }
    __syncthreads();   // lS final

    // ---- epilogue: C rows = lons (m = (lane>>4)*4+reg), cols = d (lane&15)
    {
        const float4 l4 = *(const float4*)&lS[(lane >> 4) * 4];
        const float4 rl = make_float4(1.0f / l4.x, 1.0f / l4.y, 1.0f / l4.z, 1.0f / l4.w);
        const int m0 = (lane >> 4) * 4;
        const size_t gbase = (size_t)lat * NLON + lon0 + m0;
#pragma unroll
        for (int t = 0; t < 4; ++t) {
            const int d = wv * 64 + t * 16 + (lane & 15);
            float4 o;
            o.x = acc[t].x * rl.x;
            o.y = acc[t].y * rl.y;
            o.z = acc[t].z * rl.z;
            o.w = acc[t].w * rl.w;
            *reinterpret_cast<float4*>(out + ((size_t)(b * HID + d)) * (NLAT * NLON) + gbase) = o;
        }
    }
}

extern "C" void kernel_launch(void* const* d_in, const int* in_sizes, int n_in,
                              void* d_out, int out_size, void* d_ws, size_t ws_size,
                              hipStream_t stream) {
    const float* feats  = (const float*)d_in[0];
    const float* coords = (const float*)d_in[1];
    const float* maskp  = (const float*)d_in[2];
    const float* W1     = (const float*)d_in[3];
    const float* b1     = (const float*)d_in[4];
    const float* W2     = (const float*)d_in[5];
    const float* b2     = (const float*)d_in[6];
    float* out          = (float*)d_out;

    _Float16* fhi = (_Float16*)d_ws;                     // [2][256][1024] = 1 MB
    _Float16* flo = fhi + (size_t)2 * HID * NSTA;        // [2][256][1024] = 1 MB

    hipLaunchKernelGGL(cvt_kernel, dim3(128), dim3(256), 0, stream, feats, fhi, flo);
    hipLaunchKernelGGL(s2g_kernel, dim3(1024), dim3(256), 0, stream,
                       coords, maskp, W1, b1, W2, b2, fhi, flo, out);
}

// Round 6
// 247.982 us; speedup vs baseline: 3.1257x; 1.1417x over previous
//
#include <hip/hip_runtime.h>
#include <math.h>

#define NLAT 64
#define NLON 128
#define HID  256
#define NSTA 1024
#define TG   16    // grid points (lons) per block = MFMA M
#define SC   128   // station chunk
#define NCHUNK (NSTA / SC)
#define NGRP 16    // station groups in phase A (256 threads / TG)
#define TABN 4096
#define TABW 4.5f

#define LOG2E 1.4426950408889634f
#define LN2   0.69314718055994531f

typedef float f32x4 __attribute__((ext_vector_type(4)));
typedef _Float16 f16x8 __attribute__((ext_vector_type(8)));
typedef _Float16 f16x4 __attribute__((ext_vector_type(4)));

// accurate gelu for table build (A&S 7.1.26, |erf err| <= 1.5e-7)
__device__ __forceinline__ float gelu_ref(float x) {
    const float p  = 0.3275911f;
    const float a1 = 0.254829592f, a2 = -0.284496736f, a3 = 1.421413741f,
                a4 = -1.453152027f, a5 = 1.061405429f;
    float z  = x * 0.70710678118654752f;
    float az = fabsf(z);
    float t  = __builtin_amdgcn_rcpf(fmaf(p, az, 1.0f));
    float poly = fmaf(fmaf(fmaf(fmaf(a5, t, a4), t, a3), t, a2), t, a1) * t;
    float e  = __builtin_amdgcn_exp2f(az * az * -LOG2E);
    float r  = fmaf(-poly, e, 1.0f);
    float erfz = copysignf(r, z);
    float hx = 0.5f * x;
    return fmaf(hx, erfz, hx);
}

// ---- Kernel 0: feats [b][s][d] f32 -> F^T hi/lo [b][d][s] f16 (split for precision)
__global__ __launch_bounds__(256)
void cvt_kernel(const float* __restrict__ feats, _Float16* __restrict__ fhi,
                _Float16* __restrict__ flo) {
    __shared__ float tile[16][64];
    const int blk = blockIdx.x;            // b(2) * st(64) * dt(4)
    const int b  = blk >> 8;
    const int st = (blk >> 2) & 63;
    const int dt = blk & 3;
    {
        const int s  = threadIdx.x >> 4;   // 0..15
        const int dq = threadIdx.x & 15;   // float4 col
        const float4 vv = *(const float4*)
            &feats[((size_t)(b * NSTA + st * 16 + s)) * HID + dt * 64 + dq * 4];
        *(float4*)&tile[s][dq * 4] = vv;
    }
    __syncthreads();
    const int d  = threadIdx.x >> 2;       // 0..63
    const int sq = threadIdx.x & 3;        // 4 stations each
    f16x4 hi4, lo4;
#pragma unroll
    for (int k = 0; k < 4; ++k) {
        float v = tile[sq * 4 + k][d];
        _Float16 h = (_Float16)v;
        hi4[k] = h;
        lo4[k] = (_Float16)(v - (float)h);
    }
    const size_t o = ((size_t)(b * HID + dt * 64 + d)) * NSTA + st * 16 + sq * 4;
    *(f16x4*)&fhi[o] = hi4;
    *(f16x4*)&flo[o] = lo4;
}

// ---- Main kernel: fused score MLP (LUT gelu) + online softmax + MFMA weighted sum
__global__ __launch_bounds__(256, 4)
void s2g_kernel(const float* __restrict__ coords,  // [2][1024][3]
                const float* __restrict__ maskp,   // [2][1024]
                const float* __restrict__ W1,      // [3][32]
                const float* __restrict__ b1,      // [32]
                const float* __restrict__ W2,      // [32]
                const float* __restrict__ b2p,     // [1]
                const _Float16* __restrict__ fhi,  // [2][256][1024]
                const _Float16* __restrict__ flo,  // [2][256][1024]
                float* __restrict__ out)           // [2][256][64][128]
{
    __shared__ float gtab[TABN];                   // 16 KB: gelu(x)-max(x,0) on [-4.5,4.5]
    __shared__ __align__(16) f16x8 fragAh[256];    // 4 KB: P-hi in MFMA A-frag order
    __shared__ __align__(16) f16x8 fragAl[256];    // 4 KB: P-lo
    __shared__ __align__(16) float slat[SC], slon[SC], smask[SC];
    __shared__ float4 wpack[32];                   // (W1row0, W1row1, W1row2, b1)
    __shared__ float w2s[32];
    __shared__ __align__(16) float maxbuf[NGRP * TG], psum[NGRP * TG];
    __shared__ __align__(16) float mS[TG], lS[TG], alphaS[TG];

    const int tid  = threadIdx.x;
    const int blk  = blockIdx.x & 511;     // 64 lat * 8 lon-blocks
    const int b    = blockIdx.x >> 9;      // batch
    const int lat  = blk >> 3;
    const int lon0 = (blk & 7) * TG;

    const float latv = -90.0f + (180.0f / 63.0f) * (float)lat;

    // table: cell k covers [-W + k*h, -W + (k+1)*h), value at cell center
    const float TH = 2.0f * TABW / (float)TABN;
#pragma unroll
    for (int k = tid; k < TABN; k += 256) {
        float x = -TABW + ((float)k + 0.5f) * TH;
        gtab[k] = gelu_ref(x) - fmaxf(x, 0.0f);
    }
    if (tid < 32) {
        wpack[tid] = make_float4(W1[tid], W1[32 + tid], W1[64 + tid], b1[tid]);
        w2s[tid]   = W2[tid];
        if (tid < TG) { mS[tid] = -1.0e30f; lS[tid] = 0.0f; }
    }
    const float b2 = b2p[0];

    // phase A mapping: thread -> (grid col gA, station group sgrp of 8)
    const int gA   = tid & (TG - 1);
    const int sgrp = tid >> 4;             // 0..15
    const float lonvA = -180.0f + (360.0f / 127.0f) * (float)(lon0 + gA);

    // phase C mapping: wave w owns d in [w*64, w*64+64)
    const int lane = tid & 63;
    const int wv   = tid >> 6;

    f32x4 acc[4];
#pragma unroll
    for (int t = 0; t < 4; ++t) acc[t] = (f32x4){0.0f, 0.0f, 0.0f, 0.0f};

    const float* cbase = coords + (size_t)b * NSTA * 3;
    const float* mbase = maskp  + (size_t)b * NSTA;
    const _Float16* fhb = fhi + (size_t)b * HID * NSTA;
    const _Float16* flb = flo + (size_t)b * HID * NSTA;

    const float ISCALE = (float)TABN / (2.0f * TABW);   // entries per unit
    const float IOFF   = (float)TABN * 0.5f;            // +W*ISCALE

    for (int c = 0; c < NCHUNK; ++c) {
        const int s0 = c * SC;
        __syncthreads();   // table/weights visible (c=0); prev MFMA done with frags
        if (tid < SC) {
            slat[tid]  = cbase[(size_t)(s0 + tid) * 3 + 0];
            slon[tid]  = cbase[(size_t)(s0 + tid) * 3 + 1];
            smask[tid] = mbase[s0 + tid];
        }
        __syncthreads();

        // ---- Phase A: scores for 8 stations at grid col gA (LUT gelu)
        float dist[8], dlat[8], dlon[8], v[8];
#pragma unroll
        for (int i = 0; i < 8; ++i) {
            int s = sgrp * 8 + i;
            float dla = slat[s] - latv;
            float dlo = slon[s] - lonvA;
            dlat[i] = dla;
            dlon[i] = dlo;
            dist[i] = sqrtf(fmaf(dla, dla, fmaf(dlo, dlo, 1e-6f)));
            v[i] = b2;
        }
#pragma unroll 2
        for (int j = 0; j < 32; ++j) {
            float4 wj = wpack[j];
            float  w2 = w2s[j];
#pragma unroll
            for (int i = 0; i < 8; ++i) {
                float pre = fmaf(wj.x, dist[i], fmaf(wj.y, dlat[i], fmaf(wj.z, dlon[i], wj.w)));
                float cl  = fminf(fmaxf(pre, -TABW), 4.4999f);   // v_med3_f32
                int  idx  = (int)fmaf(cl, ISCALE, IOFF);         // trunc -> cell
                float r   = gtab[idx];                            // ds gather
                v[i] = fmaf(w2, fmaxf(pre, 0.0f), v[i]);
                v[i] = fmaf(w2, r, v[i]);
            }
        }
        float lmax = -3.0e38f;
#pragma unroll
        for (int i = 0; i < 8; ++i) {
            int s = sgrp * 8 + i;
            float x  = v[i];
            float ax = fabsf(x);
            float e  = __builtin_amdgcn_exp2f(-ax * LOG2E);
            float sp = fmaxf(x, 0.0f) + __builtin_amdgcn_logf(1.0f + e) * LN2;
            v[i] = sp * smask[s];
            lmax = fmaxf(lmax, v[i]);
        }
        maxbuf[sgrp * TG + gA] = lmax;
        __syncthreads();

        // ---- B1: running max + rescale factor per grid col
        if (tid < TG) {
            float cm = maxbuf[tid];
#pragma unroll
            for (int k = 1; k < NGRP; ++k) cm = fmaxf(cm, maxbuf[k * TG + tid]);
            float mold = mS[tid];
            float mnew = fmaxf(mold, cm);
            alphaS[tid] = __builtin_amdgcn_exp2f((mold - mnew) * LOG2E);
            mS[tid] = mnew;
        }
        __syncthreads();

        // ---- B2: p = exp(v-m) -> f16 hi+lo, A-frag layout; sum fp32 p
        {
            float m  = mS[gA];
            float ps = 0.0f;
            f16x8 fh, fl;
#pragma unroll
            for (int i = 0; i < 8; ++i) {
                float p = __builtin_amdgcn_exp2f((v[i] - m) * LOG2E);
                _Float16 h = (_Float16)p;
                fh[i] = h;
                fl[i] = (_Float16)(p - (float)h);
                ps += p;
            }
            const int idx = ((sgrp >> 2) << 6) + (((sgrp & 3) << 4) | gA);
            fragAh[idx] = fh;
            fragAl[idx] = fl;
            psum[sgrp * TG + gA] = ps;
        }
        __syncthreads();

        // ---- B3: denominator update (runs alongside phase C)
        if (tid < TG) {
            float t = 0.0f;
#pragma unroll
            for (int k = 0; k < NGRP; ++k) t += psum[k * TG + tid];
            lS[tid] = lS[tid] * alphaS[tid] + t;
        }

        // ---- Phase C: rescale accumulators (rows m = (lane>>4)*4+reg), MFMA
        {
            const f32x4 al = *(const f32x4*)&alphaS[(lane >> 4) * 4];
#pragma unroll
            for (int t = 0; t < 4; ++t) acc[t] = acc[t] * al;

            const int srow = s0 + ((lane >> 4) * 8);
            const int dbase = wv * 64 + (lane & 15);
#pragma unroll
            for (int kc = 0; kc < 4; ++kc) {
                f16x8 ah = fragAh[(kc << 6) + lane];
                f16x8 al16 = fragAl[(kc << 6) + lane];
#pragma unroll
                for (int t = 0; t < 4; ++t) {
                    const size_t off = (size_t)(dbase + t * 16) * NSTA + srow + kc * 32;
                    f16x8 bh = *(const f16x8*)(fhb + off);
                    f16x8 bl = *(const f16x8*)(flb + off);
                    acc[t] = __builtin_amdgcn_mfma_f32_16x16x32_f16(ah, bh, acc[t], 0, 0, 0);
                    acc[t] = __builtin_amdgcn_mfma_f32_16x16x32_f16(ah, bl, acc[t], 0, 0, 0);
                    acc[t] = __builtin_amdgcn_mfma_f32_16x16x32_f16(al16, bh, acc[t], 0, 0, 0);
                }
            }
        }
    }
    __syncthreads();   // lS final

    // ---- epilogue: C rows = lons (m = (lane>>4)*4+reg), cols = d (lane&15)
    {
        const float4 l4 = *(const float4*)&lS[(lane >> 4) * 4];
        const float4 rl = make_float4(1.0f / l4.x, 1.0f / l4.y, 1.0f / l4.z, 1.0f / l4.w);
        const int m0 = (lane >> 4) * 4;
        const size_t gbase = (size_t)lat * NLON + lon0 + m0;
#pragma unroll
        for (int t = 0; t < 4; ++t) {
            const int d = wv * 64 + t * 16 + (lane & 15);
            float4 o;
            o.x = acc[t].x * rl.x;
            o.y = acc[t].y * rl.y;
            o.z = acc[t].z * rl.z;
            o.w = acc[t].w * rl.w;
            *reinterpret_cast<float4*>(out + ((size_t)(b * HID + d)) * (NLAT * NLON) + gbase) = o;
        }
    }
}

extern "C" void kernel_launch(void* const* d_in, const int* in_sizes, int n_in,
                              void* d_out, int out_size, void* d_ws, size_t ws_size,
                              hipStream_t stream) {
    const float* feats  = (const float*)d_in[0];
    const float* coords = (const float*)d_in[1];
    const float* maskp  = (const float*)d_in[2];
    const float* W1     = (const float*)d_in[3];
    const float* b1     = (const float*)d_in[4];
    const float* W2     = (const float*)d_in[5];
    const float* b2     = (const float*)d_in[6];
    float* out          = (float*)d_out;

    _Float16* fhi = (_Float16*)d_ws;                     // [2][256][1024] = 1 MB
    _Float16* flo = fhi + (size_t)2 * HID * NSTA;        // [2][256][1024] = 1 MB

    hipLaunchKernelGGL(cvt_kernel, dim3(512), dim3(256), 0, stream, feats, fhi, flo);
    hipLaunchKernelGGL(s2g_kernel, dim3(1024), dim3(256), 0, stream,
                       coords, maskp, W1, b1, W2, b2, fhi, flo, out);
}